// Round 1
// baseline (3161.240 us; speedup 1.0000x reference)
//
#include <hip/hip_runtime.h>
#include <math.h>

#define TC 64           // time chunk
#define T_TOTAL 512
#define BATCH 512
#define D_IN 300
#define H1 128
#define G1 512          // 4*H1
#define H2 32
#define G2 128          // 4*H2
#define NCLS 14

__device__ __forceinline__ float sigmoid_f(float x) {
    return __fdividef(1.0f, 1.0f + __expf(-x));
}
__device__ __forceinline__ float tanh_f(float x) {
    float xc = fminf(fmaxf(x, -15.f), 15.f);
    float e = __expf(2.0f * xc);
    return __fdividef(e - 1.0f, e + 1.0f);
}

// ---------------------------------------------------------------------------
// Generic fp32 tiled GEMM:  C[M,N] = A[M,K] @ B[K,N] + bias[N]
// A row address = base + (m>>6)*rowBlockStride + (m&63)*rowStride  (floats)
// BM=64, BN=64, BK=64, 256 threads, 4x4 micro-tile.
// M, N multiples of 64. K arbitrary (zero-filled tail).
// ---------------------------------------------------------------------------
__global__ __launch_bounds__(256, 2)
void gemm_bias(const float* __restrict__ A, long rowStride, long rowBlockStride,
               const float* __restrict__ B, const float* __restrict__ bias,
               float* __restrict__ C, int N, int K)
{
    __shared__ float As[64][68];   // [kk][row], padded (68*4=272B, 16B-mult)
    __shared__ float Bs[64][68];   // [kk][col]

    const int tid = threadIdx.x;
    const int tx = tid & 15, ty = tid >> 4;
    const int m0 = blockIdx.y * 64;
    const int n0 = blockIdx.x * 64;

    float acc[4][4];
#pragma unroll
    for (int i = 0; i < 4; i++)
#pragma unroll
        for (int j = 0; j < 4; j++)
            acc[i][j] = bias[n0 + tx * 4 + j];

    const int arow  = tid >> 2;          // 0..63
    const int akoff = (tid & 3) * 16;    // 0,16,32,48
    const float* Arow = A + (long)((m0 + arow) >> 6) * rowBlockStride
                          + (long)((m0 + arow) & 63) * rowStride;
    const int bkk   = tid >> 2;          // 0..63
    const int bnoff = (tid & 3) * 16;

    for (int k0 = 0; k0 < K; k0 += 64) {
        // stage A (transposed into As[kk][row])
#pragma unroll
        for (int i = 0; i < 4; i++) {
            int kk = akoff + i * 4;
            int kg = k0 + kk;
            float4 v = {0.f, 0.f, 0.f, 0.f};
            if (kg + 3 < K) {
                v = *(const float4*)(Arow + kg);
            } else {
                if (kg + 0 < K) v.x = Arow[kg + 0];
                if (kg + 1 < K) v.y = Arow[kg + 1];
                if (kg + 2 < K) v.z = Arow[kg + 2];
                if (kg + 3 < K) v.w = Arow[kg + 3];
            }
            As[kk + 0][arow] = v.x;
            As[kk + 1][arow] = v.y;
            As[kk + 2][arow] = v.z;
            As[kk + 3][arow] = v.w;
        }
        // stage B
#pragma unroll
        for (int i = 0; i < 4; i++) {
            int nn = bnoff + i * 4;
            int kg = k0 + bkk;
            float4 v = {0.f, 0.f, 0.f, 0.f};
            if (kg < K) v = *(const float4*)(B + (long)kg * N + n0 + nn);
            *(float4*)&Bs[bkk][nn] = v;
        }
        __syncthreads();

#pragma unroll
        for (int kk = 0; kk < 64; kk++) {
            float4 a = *(const float4*)&As[kk][ty * 4];
            float4 b = *(const float4*)&Bs[kk][tx * 4];
            acc[0][0] += a.x * b.x; acc[0][1] += a.x * b.y; acc[0][2] += a.x * b.z; acc[0][3] += a.x * b.w;
            acc[1][0] += a.y * b.x; acc[1][1] += a.y * b.y; acc[1][2] += a.y * b.z; acc[1][3] += a.y * b.w;
            acc[2][0] += a.z * b.x; acc[2][1] += a.z * b.y; acc[2][2] += a.z * b.z; acc[2][3] += a.z * b.w;
            acc[3][0] += a.w * b.x; acc[3][1] += a.w * b.y; acc[3][2] += a.w * b.z; acc[3][3] += a.w * b.w;
        }
        __syncthreads();
    }

#pragma unroll
    for (int i = 0; i < 4; i++) {
        float4 v = {acc[i][0], acc[i][1], acc[i][2], acc[i][3]};
        *(float4*)(C + (long)(m0 + ty * 4 + i) * N + n0 + tx * 4) = v;
    }
}

// ---------------------------------------------------------------------------
// Transpose U1 [128,512] -> U1T [512,128]; U2 [32,128] -> U2T [128,32]
// ---------------------------------------------------------------------------
__global__ void transpose_U(const float* __restrict__ U1, float* __restrict__ U1T,
                            const float* __restrict__ U2, float* __restrict__ U2T)
{
    int idx = blockIdx.x * 256 + threadIdx.x;
    if (idx < 128 * 512) {
        int k = idx / 512, j = idx % 512;
        U1T[j * 128 + k] = U1[idx];
    }
    if (idx < 32 * 128) {
        int k = idx / 128, j = idx % 128;
        U2T[j * 32 + k] = U2[idx];
    }
}

// ---------------------------------------------------------------------------
// LSTM1 scan over one T-chunk. 256 WGs x 512 threads; each WG owns 2 batch
// rows through all TC steps. Thread j owns U1 column j in 128 VGPRs.
// ---------------------------------------------------------------------------
__global__ __launch_bounds__(512)
void lstm1_scan(const float* __restrict__ xz,     // [B][TC][512]
                const float* __restrict__ U1T,    // [512][128]
                float* __restrict__ h1out,        // [B][TC][128]
                float* __restrict__ stateH,       // [B][128]
                float* __restrict__ stateC,       // [B][128]
                int firstChunk)
{
    const int j  = threadIdx.x;        // gate column 0..511
    const int b0 = blockIdx.x * 2;

    __shared__ __align__(16) float hs[2][128];
    __shared__ __align__(16) float gs[2][512];

    float U[128];
#pragma unroll
    for (int k = 0; k < 128; k += 4)
        *(float4*)&U[k] = *(const float4*)&U1T[j * 128 + k];

    const int cb = j >> 7;             // valid for j<256
    const int cn = j & 127;
    float creg = 0.f, hreg = 0.f;
    if (j < 256) {
        if (firstChunk) {
            hs[cb][cn] = 0.f;
        } else {
            hs[cb][cn] = stateH[(b0 + cb) * 128 + cn];
            creg       = stateC[(b0 + cb) * 128 + cn];
        }
    }
    __syncthreads();

    const float* xzp0 = xz + ((long)b0 * TC) * 512 + j;
    const float* xzp1 = xz + ((long)(b0 + 1) * TC) * 512 + j;
    float x0 = xzp0[0], x1 = xzp1[0];

    const bool is_g = (j >= 256) && (j < 384);

    for (int t = 0; t < TC; t++) {
        float xn0 = 0.f, xn1 = 0.f;
        if (t + 1 < TC) { xn0 = xzp0[(t + 1) * 512]; xn1 = xzp1[(t + 1) * 512]; }

        float a0a = x0, a0b = 0.f, a1a = x1, a1b = 0.f;
#pragma unroll
        for (int k = 0; k < 128; k += 4) {
            float4 h0 = *(const float4*)&hs[0][k];
            float4 h1 = *(const float4*)&hs[1][k];
            a0a += h0.x * U[k];     a0b += h0.y * U[k + 1];
            a0a += h0.z * U[k + 2]; a0b += h0.w * U[k + 3];
            a1a += h1.x * U[k];     a1b += h1.y * U[k + 1];
            a1a += h1.z * U[k + 2]; a1b += h1.w * U[k + 3];
        }
        float a0 = a0a + a0b, a1 = a1a + a1b;

        float g0 = is_g ? tanh_f(a0) : sigmoid_f(a0);
        float g1 = is_g ? tanh_f(a1) : sigmoid_f(a1);
        gs[0][j] = g0;
        gs[1][j] = g1;
        __syncthreads();

        if (j < 256) {
            float iv = gs[cb][cn];
            float fv = gs[cb][128 + cn];
            float gv = gs[cb][256 + cn];
            float ov = gs[cb][384 + cn];
            creg = fv * creg + iv * gv;
            hreg = ov * tanh_f(creg);
            hs[cb][cn] = hreg;
            h1out[((long)(b0 + cb) * TC + t) * 128 + cn] = hreg;
        }
        __syncthreads();

        x0 = xn0; x1 = xn1;
    }

    if (j < 256) {
        stateH[(b0 + cb) * 128 + cn] = hreg;
        stateC[(b0 + cb) * 128 + cn] = creg;
    }
}

// ---------------------------------------------------------------------------
// LSTM2 scan over one T-chunk. 256 WGs x 128 threads; 2 batch rows per WG.
// Only carry state is kept (h sequence not needed).
// ---------------------------------------------------------------------------
__global__ __launch_bounds__(128)
void lstm2_scan(const float* __restrict__ xz2,    // [B][TC][128]
                const float* __restrict__ U2T,    // [128][32]
                float* __restrict__ stateH,       // [B][32]
                float* __restrict__ stateC,       // [B][32]
                int firstChunk)
{
    const int j  = threadIdx.x;        // 0..127
    const int b0 = blockIdx.x * 2;

    __shared__ __align__(16) float hs[2][32];
    __shared__ __align__(16) float gs[2][128];

    float U[32];
#pragma unroll
    for (int k = 0; k < 32; k += 4)
        *(float4*)&U[k] = *(const float4*)&U2T[j * 32 + k];

    const int cb = j >> 5;             // valid for j<64
    const int cn = j & 31;
    float creg = 0.f, hreg = 0.f;
    if (j < 64) {
        if (firstChunk) {
            hs[cb][cn] = 0.f;
        } else {
            hs[cb][cn] = stateH[(b0 + cb) * 32 + cn];
            creg       = stateC[(b0 + cb) * 32 + cn];
        }
    }
    __syncthreads();

    const float* xzp0 = xz2 + ((long)b0 * TC) * 128 + j;
    const float* xzp1 = xz2 + ((long)(b0 + 1) * TC) * 128 + j;
    float x0 = xzp0[0], x1 = xzp1[0];

    const bool is_g = (j >= 64) && (j < 96);

    for (int t = 0; t < TC; t++) {
        float xn0 = 0.f, xn1 = 0.f;
        if (t + 1 < TC) { xn0 = xzp0[(t + 1) * 128]; xn1 = xzp1[(t + 1) * 128]; }

        float a0 = x0, a1 = x1;
#pragma unroll
        for (int k = 0; k < 32; k += 4) {
            float4 h0 = *(const float4*)&hs[0][k];
            float4 h1 = *(const float4*)&hs[1][k];
            a0 += h0.x * U[k];     a0 += h0.y * U[k + 1];
            a0 += h0.z * U[k + 2]; a0 += h0.w * U[k + 3];
            a1 += h1.x * U[k];     a1 += h1.y * U[k + 1];
            a1 += h1.z * U[k + 2]; a1 += h1.w * U[k + 3];
        }

        float g0 = is_g ? tanh_f(a0) : sigmoid_f(a0);
        float g1 = is_g ? tanh_f(a1) : sigmoid_f(a1);
        gs[0][j] = g0;
        gs[1][j] = g1;
        __syncthreads();

        if (j < 64) {
            float iv = gs[cb][cn];
            float fv = gs[cb][32 + cn];
            float gv = gs[cb][64 + cn];
            float ov = gs[cb][96 + cn];
            creg = fv * creg + iv * gv;
            hreg = ov * tanh_f(creg);
            hs[cb][cn] = hreg;
        }
        __syncthreads();

        x0 = xn0; x1 = xn1;
    }

    if (j < 64) {
        stateH[(b0 + cb) * 32 + cn] = hreg;
        stateC[(b0 + cb) * 32 + cn] = creg;
    }
}

// ---------------------------------------------------------------------------
// Head: out = softmax(h2_last @ Wd + bd)   [512,32]@[32,14]
// ---------------------------------------------------------------------------
__global__ __launch_bounds__(256)
void head_kernel(const float* __restrict__ h2, const float* __restrict__ Wd,
                 const float* __restrict__ bd, float* __restrict__ out)
{
    int b = blockIdx.x * 256 + threadIdx.x;   // 0..511
    float h[H2];
#pragma unroll
    for (int k = 0; k < H2; k += 4)
        *(float4*)&h[k] = *(const float4*)&h2[b * H2 + k];

    float lg[NCLS];
#pragma unroll
    for (int c = 0; c < NCLS; c++) lg[c] = bd[c];
#pragma unroll
    for (int k = 0; k < H2; k++) {
        float hv = h[k];
#pragma unroll
        for (int c = 0; c < NCLS; c++)
            lg[c] += hv * Wd[k * NCLS + c];
    }
    float m = lg[0];
#pragma unroll
    for (int c = 1; c < NCLS; c++) m = fmaxf(m, lg[c]);
    float s = 0.f;
#pragma unroll
    for (int c = 0; c < NCLS; c++) { lg[c] = __expf(lg[c] - m); s += lg[c]; }
    float inv = __fdividef(1.0f, s);
#pragma unroll
    for (int c = 0; c < NCLS; c++) out[b * NCLS + c] = lg[c] * inv;
}

// ---------------------------------------------------------------------------
extern "C" void kernel_launch(void* const* d_in, const int* in_sizes, int n_in,
                              void* d_out, int out_size, void* d_ws, size_t ws_size,
                              hipStream_t stream)
{
    const float* x  = (const float*)d_in[0];
    const float* W1 = (const float*)d_in[1];
    const float* U1 = (const float*)d_in[2];
    const float* b1 = (const float*)d_in[3];
    const float* W2 = (const float*)d_in[4];
    const float* U2 = (const float*)d_in[5];
    const float* b2 = (const float*)d_in[6];
    const float* Wd = (const float*)d_in[7];
    const float* bd = (const float*)d_in[8];
    float* out = (float*)d_out;

    char* ws = (char*)d_ws;
    float* xz1 = (float*)(ws);                       // 512*64*512*4 = 67108864
    float* h1c = (float*)(ws + 67108864);            // 512*64*128*4 = 16777216
    float* xz2 = (float*)(ws + 83886080);            // 16777216
    float* s1h = (float*)(ws + 100663296);           // 262144
    float* s1c = (float*)(ws + 100925440);           // 262144
    float* s2h = (float*)(ws + 101187584);           // 65536
    float* s2c = (float*)(ws + 101253120);           // 65536
    float* U1T = (float*)(ws + 101318656);           // 262144
    float* U2T = (float*)(ws + 101580800);           // 16384

    transpose_U<<<256, 256, 0, stream>>>(U1, U1T, U2, U2T);

    for (int c = 0; c < T_TOTAL / TC; c++) {
        const float* xchunk = x + (long)c * TC * D_IN;
        // xz1 = x_chunk @ W1 + b1   (M=32768, N=512, K=300)
        gemm_bias<<<dim3(G1 / 64, (BATCH * TC) / 64), 256, 0, stream>>>(
            xchunk, (long)D_IN, (long)T_TOTAL * D_IN, W1, b1, xz1, G1, D_IN);
        // scan LSTM1 over this chunk
        lstm1_scan<<<BATCH / 2, 512, 0, stream>>>(xz1, U1T, h1c, s1h, s1c, c == 0);
        // xz2 = h1_chunk @ W2 + b2  (M=32768, N=128, K=128)
        gemm_bias<<<dim3(G2 / 64, (BATCH * TC) / 64), 256, 0, stream>>>(
            h1c, (long)H1, (long)TC * H1, W2, b2, xz2, G2, H1);
        // scan LSTM2 over this chunk
        lstm2_scan<<<BATCH / 2, 128, 0, stream>>>(xz2, U2T, s2h, s2c, c == 0);
    }

    head_kernel<<<BATCH / 256, 256, 0, stream>>>(s2h, Wd, bd, out);
}

// Round 2
// 2585.178 us; speedup vs baseline: 1.2228x; 1.2228x over previous
//
#include <hip/hip_runtime.h>
#include <math.h>

#define TC 64           // time chunk
#define T_TOTAL 512
#define BATCH 512
#define D_IN 300
#define H1 128
#define G1 512          // 4*H1
#define H2 32
#define G2 128          // 4*H2
#define NCLS 14
#define KP1 320         // D_IN padded to mult of 32

typedef __attribute__((ext_vector_type(8))) __bf16 bf16x8;
typedef __attribute__((ext_vector_type(4))) float f32x4;

__device__ __forceinline__ float sigmoid_f(float x) {
    return __fdividef(1.0f, 1.0f + __expf(-x));
}
__device__ __forceinline__ float tanh_f(float x) {
    float xc = fminf(fmaxf(x, -15.f), 15.f);
    float e = __expf(2.0f * xc);
    return __fdividef(e - 1.0f, e + 1.0f);
}
__device__ __forceinline__ unsigned short f2bf(float x) {
    unsigned int u = __float_as_uint(x);
    unsigned int r = u + 0x7fffu + ((u >> 16) & 1u);
    return (unsigned short)(r >> 16);
}
__device__ __forceinline__ float bf2f(unsigned short h) {
    return __uint_as_float(((unsigned int)h) << 16);
}

// ---------------------------------------------------------------------------
// MFMA GEMM, bf16 hi/lo split (3 products, fp32 accum):
//   C[M,N] = A[M,K] @ B[K,N] + bias[N]
// A fp32, row address = base + (m>>6)*rowBlockStride + (m&63)*rowStride.
// BT: pre-split bf16 planes, [N][Kp] hi, then lo at +bplane (ushort units).
// Block tile 128x128, 4 waves (2x2), each wave 64x64 = 4x4 frags of 16x16x32.
// ---------------------------------------------------------------------------
__global__ __launch_bounds__(256, 2)
void gemm_mfma_bias(const float* __restrict__ A, long rowStride, long rowBlockStride,
                    const unsigned short* __restrict__ BT, long bplane,
                    const float* __restrict__ bias, float* __restrict__ C,
                    int N, int K, int Kp)
{
    __shared__ unsigned short As[2][128][40];   // [hi/lo][row][k], 80B row stride

    const int tid = threadIdx.x;
    const int l   = tid & 63;
    const int w   = tid >> 6;
    const int wm  = w >> 1, wn = w & 1;
    const int m0  = blockIdx.y * 128;
    const int n0  = blockIdx.x * 128;

    // A staging: thread -> (row, 16-wide k segment)
    const int srow = tid >> 1;
    const int skb  = (tid & 1) * 16;
    const long mg  = m0 + srow;
    const float* Arow = A + (mg >> 6) * rowBlockStride + (mg & 63) * rowStride;

    const int lr   = l & 15;        // frag row/col within 16
    const int koff = (l >> 4) * 8;  // k group

    f32x4 acc[4][4];
#pragma unroll
    for (int i = 0; i < 4; i++)
#pragma unroll
        for (int j = 0; j < 4; j++)
            acc[i][j] = (f32x4){0.f, 0.f, 0.f, 0.f};

    for (int k0 = 0; k0 < Kp; k0 += 32) {
        // ---- stage A hi/lo into LDS ----
#pragma unroll
        for (int i = 0; i < 4; i++) {
            int kg = k0 + skb + i * 4;
            float4 v = {0.f, 0.f, 0.f, 0.f};
            if (kg + 3 < K) {
                v = *(const float4*)(Arow + kg);
            } else {
                if (kg + 0 < K) v.x = Arow[kg + 0];
                if (kg + 1 < K) v.y = Arow[kg + 1];
                if (kg + 2 < K) v.z = Arow[kg + 2];
                if (kg + 3 < K) v.w = Arow[kg + 3];
            }
            ushort4 hi, lo;
            hi.x = f2bf(v.x); lo.x = f2bf(v.x - bf2f(hi.x));
            hi.y = f2bf(v.y); lo.y = f2bf(v.y - bf2f(hi.y));
            hi.z = f2bf(v.z); lo.z = f2bf(v.z - bf2f(hi.z));
            hi.w = f2bf(v.w); lo.w = f2bf(v.w - bf2f(hi.w));
            *(ushort4*)&As[0][srow][skb + i * 4] = hi;
            *(ushort4*)&As[1][srow][skb + i * 4] = lo;
        }
        __syncthreads();

        // ---- B fragments straight from global (pre-split planes) ----
        bf16x8 bh[4], bl[4];
#pragma unroll
        for (int fj = 0; fj < 4; fj++) {
            const unsigned short* bp = BT + (long)(n0 + wn * 64 + fj * 16 + lr) * Kp + k0 + koff;
            bh[fj] = *(const bf16x8*)bp;
            bl[fj] = *(const bf16x8*)(bp + bplane);
        }

        // ---- A fragments + MFMA (3 products) ----
#pragma unroll
        for (int fi = 0; fi < 4; fi++) {
            int ar = wm * 64 + fi * 16 + lr;
            bf16x8 ah = *(const bf16x8*)&As[0][ar][koff];
            bf16x8 al = *(const bf16x8*)&As[1][ar][koff];
#pragma unroll
            for (int fj = 0; fj < 4; fj++) {
                acc[fi][fj] = __builtin_amdgcn_mfma_f32_16x16x32_bf16(ah, bh[fj], acc[fi][fj], 0, 0, 0);
                acc[fi][fj] = __builtin_amdgcn_mfma_f32_16x16x32_bf16(ah, bl[fj], acc[fi][fj], 0, 0, 0);
                acc[fi][fj] = __builtin_amdgcn_mfma_f32_16x16x32_bf16(al, bh[fj], acc[fi][fj], 0, 0, 0);
            }
        }
        __syncthreads();
    }

    // ---- epilogue: +bias, store (D: col=lane&15, row=(lane>>4)*4+r) ----
#pragma unroll
    for (int fj = 0; fj < 4; fj++) {
        int col = n0 + wn * 64 + fj * 16 + lr;
        float bv = bias[col];
#pragma unroll
        for (int fi = 0; fi < 4; fi++) {
            int row = m0 + wm * 64 + fi * 16 + (l >> 4) * 4;
#pragma unroll
            for (int r = 0; r < 4; r++)
                C[(long)(row + r) * N + col] = acc[fi][fj][r] + bv;
        }
    }
}

// ---------------------------------------------------------------------------
// Prep: transpose U1/U2 (fp32) and pre-split W1^T/W2^T into bf16 hi/lo planes.
// W1T: [512][320] hi then lo (ushort). W2T: [128][128] hi then lo.
// ---------------------------------------------------------------------------
__global__ void prep_weights(const float* __restrict__ U1, float* __restrict__ U1T,
                             const float* __restrict__ U2, float* __restrict__ U2T,
                             const float* __restrict__ W1, unsigned short* __restrict__ W1T,
                             const float* __restrict__ W2, unsigned short* __restrict__ W2T)
{
    int idx = blockIdx.x * 256 + threadIdx.x;
    if (idx < 128 * 512) {
        int k = idx / 512, j = idx % 512;
        U1T[j * 128 + k] = U1[idx];
    }
    if (idx < 32 * 128) {
        int k = idx / 128, j = idx % 128;
        U2T[j * 32 + k] = U2[idx];
    }
    if (idx < 512 * KP1) {
        int j = idx / KP1, k = idx % KP1;
        float v = (k < D_IN) ? W1[k * G1 + j] : 0.f;
        unsigned short hi = f2bf(v);
        unsigned short lo = f2bf(v - bf2f(hi));
        W1T[j * KP1 + k] = hi;
        W1T[512 * KP1 + j * KP1 + k] = lo;
    }
    if (idx < 128 * 128) {
        int j = idx / 128, k = idx % 128;
        float v = W2[k * G2 + j];
        unsigned short hi = f2bf(v);
        unsigned short lo = f2bf(v - bf2f(hi));
        W2T[j * 128 + k] = hi;
        W2T[128 * 128 + j * 128 + k] = lo;
    }
}

// ---------------------------------------------------------------------------
// LSTM1 scan over one T-chunk. 256 WGs x 512 threads; each WG owns 2 batch
// rows through all TC steps. Thread j owns U1 column j in 128 VGPRs.
// ---------------------------------------------------------------------------
__global__ __launch_bounds__(512)
void lstm1_scan(const float* __restrict__ xz,     // [B][TC][512]
                const float* __restrict__ U1T,    // [512][128]
                float* __restrict__ h1out,        // [B][TC][128]
                float* __restrict__ stateH,       // [B][128]
                float* __restrict__ stateC,       // [B][128]
                int firstChunk)
{
    const int j  = threadIdx.x;        // gate column 0..511
    const int b0 = blockIdx.x * 2;

    __shared__ __align__(16) float hs[2][128];
    __shared__ __align__(16) float gs[2][512];

    float U[128];
#pragma unroll
    for (int k = 0; k < 128; k += 4)
        *(float4*)&U[k] = *(const float4*)&U1T[j * 128 + k];

    const int cb = j >> 7;             // valid for j<256
    const int cn = j & 127;
    float creg = 0.f, hreg = 0.f;
    if (j < 256) {
        if (firstChunk) {
            hs[cb][cn] = 0.f;
        } else {
            hs[cb][cn] = stateH[(b0 + cb) * 128 + cn];
            creg       = stateC[(b0 + cb) * 128 + cn];
        }
    }
    __syncthreads();

    const float* xzp0 = xz + ((long)b0 * TC) * 512 + j;
    const float* xzp1 = xz + ((long)(b0 + 1) * TC) * 512 + j;
    float x0 = xzp0[0], x1 = xzp1[0];

    const bool is_g = (j >= 256) && (j < 384);

    for (int t = 0; t < TC; t++) {
        float xn0 = 0.f, xn1 = 0.f;
        if (t + 1 < TC) { xn0 = xzp0[(t + 1) * 512]; xn1 = xzp1[(t + 1) * 512]; }

        float a0a = x0, a0b = 0.f, a1a = x1, a1b = 0.f;
#pragma unroll
        for (int k = 0; k < 128; k += 4) {
            float4 h0 = *(const float4*)&hs[0][k];
            float4 h1 = *(const float4*)&hs[1][k];
            a0a += h0.x * U[k];     a0b += h0.y * U[k + 1];
            a0a += h0.z * U[k + 2]; a0b += h0.w * U[k + 3];
            a1a += h1.x * U[k];     a1b += h1.y * U[k + 1];
            a1a += h1.z * U[k + 2]; a1b += h1.w * U[k + 3];
        }
        float a0 = a0a + a0b, a1 = a1a + a1b;

        float g0 = is_g ? tanh_f(a0) : sigmoid_f(a0);
        float g1 = is_g ? tanh_f(a1) : sigmoid_f(a1);
        gs[0][j] = g0;
        gs[1][j] = g1;
        __syncthreads();

        if (j < 256) {
            float iv = gs[cb][cn];
            float fv = gs[cb][128 + cn];
            float gv = gs[cb][256 + cn];
            float ov = gs[cb][384 + cn];
            creg = fv * creg + iv * gv;
            hreg = ov * tanh_f(creg);
            hs[cb][cn] = hreg;
            h1out[((long)(b0 + cb) * TC + t) * 128 + cn] = hreg;
        }
        __syncthreads();

        x0 = xn0; x1 = xn1;
    }

    if (j < 256) {
        stateH[(b0 + cb) * 128 + cn] = hreg;
        stateC[(b0 + cb) * 128 + cn] = creg;
    }
}

// ---------------------------------------------------------------------------
// LSTM2 scan over one T-chunk. 256 WGs x 128 threads; 2 batch rows per WG.
// ---------------------------------------------------------------------------
__global__ __launch_bounds__(128)
void lstm2_scan(const float* __restrict__ xz2,    // [B][TC][128]
                const float* __restrict__ U2T,    // [128][32]
                float* __restrict__ stateH,       // [B][32]
                float* __restrict__ stateC,       // [B][32]
                int firstChunk)
{
    const int j  = threadIdx.x;        // 0..127
    const int b0 = blockIdx.x * 2;

    __shared__ __align__(16) float hs[2][32];
    __shared__ __align__(16) float gs[2][128];

    float U[32];
#pragma unroll
    for (int k = 0; k < 32; k += 4)
        *(float4*)&U[k] = *(const float4*)&U2T[j * 32 + k];

    const int cb = j >> 5;             // valid for j<64
    const int cn = j & 31;
    float creg = 0.f, hreg = 0.f;
    if (j < 64) {
        if (firstChunk) {
            hs[cb][cn] = 0.f;
        } else {
            hs[cb][cn] = stateH[(b0 + cb) * 32 + cn];
            creg       = stateC[(b0 + cb) * 32 + cn];
        }
    }
    __syncthreads();

    const float* xzp0 = xz2 + ((long)b0 * TC) * 128 + j;
    const float* xzp1 = xz2 + ((long)(b0 + 1) * TC) * 128 + j;
    float x0 = xzp0[0], x1 = xzp1[0];

    const bool is_g = (j >= 64) && (j < 96);

    for (int t = 0; t < TC; t++) {
        float xn0 = 0.f, xn1 = 0.f;
        if (t + 1 < TC) { xn0 = xzp0[(t + 1) * 128]; xn1 = xzp1[(t + 1) * 128]; }

        float a0 = x0, a1 = x1;
#pragma unroll
        for (int k = 0; k < 32; k += 4) {
            float4 h0 = *(const float4*)&hs[0][k];
            float4 h1 = *(const float4*)&hs[1][k];
            a0 += h0.x * U[k];     a0 += h0.y * U[k + 1];
            a0 += h0.z * U[k + 2]; a0 += h0.w * U[k + 3];
            a1 += h1.x * U[k];     a1 += h1.y * U[k + 1];
            a1 += h1.z * U[k + 2]; a1 += h1.w * U[k + 3];
        }

        float g0 = is_g ? tanh_f(a0) : sigmoid_f(a0);
        float g1 = is_g ? tanh_f(a1) : sigmoid_f(a1);
        gs[0][j] = g0;
        gs[1][j] = g1;
        __syncthreads();

        if (j < 64) {
            float iv = gs[cb][cn];
            float fv = gs[cb][32 + cn];
            float gv = gs[cb][64 + cn];
            float ov = gs[cb][96 + cn];
            creg = fv * creg + iv * gv;
            hreg = ov * tanh_f(creg);
            hs[cb][cn] = hreg;
        }
        __syncthreads();

        x0 = xn0; x1 = xn1;
    }

    if (j < 64) {
        stateH[(b0 + cb) * 32 + cn] = hreg;
        stateC[(b0 + cb) * 32 + cn] = creg;
    }
}

// ---------------------------------------------------------------------------
// Head: out = softmax(h2_last @ Wd + bd)   [512,32]@[32,14]
// ---------------------------------------------------------------------------
__global__ __launch_bounds__(256)
void head_kernel(const float* __restrict__ h2, const float* __restrict__ Wd,
                 const float* __restrict__ bd, float* __restrict__ out)
{
    int b = blockIdx.x * 256 + threadIdx.x;   // 0..511
    float h[H2];
#pragma unroll
    for (int k = 0; k < H2; k += 4)
        *(float4*)&h[k] = *(const float4*)&h2[b * H2 + k];

    float lg[NCLS];
#pragma unroll
    for (int c = 0; c < NCLS; c++) lg[c] = bd[c];
#pragma unroll
    for (int k = 0; k < H2; k++) {
        float hv = h[k];
#pragma unroll
        for (int c = 0; c < NCLS; c++)
            lg[c] += hv * Wd[k * NCLS + c];
    }
    float m = lg[0];
#pragma unroll
    for (int c = 1; c < NCLS; c++) m = fmaxf(m, lg[c]);
    float s = 0.f;
#pragma unroll
    for (int c = 0; c < NCLS; c++) { lg[c] = __expf(lg[c] - m); s += lg[c]; }
    float inv = __fdividef(1.0f, s);
#pragma unroll
    for (int c = 0; c < NCLS; c++) out[b * NCLS + c] = lg[c] * inv;
}

// ---------------------------------------------------------------------------
extern "C" void kernel_launch(void* const* d_in, const int* in_sizes, int n_in,
                              void* d_out, int out_size, void* d_ws, size_t ws_size,
                              hipStream_t stream)
{
    const float* x  = (const float*)d_in[0];
    const float* W1 = (const float*)d_in[1];
    const float* U1 = (const float*)d_in[2];
    const float* b1 = (const float*)d_in[3];
    const float* W2 = (const float*)d_in[4];
    const float* U2 = (const float*)d_in[5];
    const float* b2 = (const float*)d_in[6];
    const float* Wd = (const float*)d_in[7];
    const float* bd = (const float*)d_in[8];
    float* out = (float*)d_out;

    char* ws = (char*)d_ws;
    float* xz1 = (float*)(ws);                       // 512*64*512*4 = 67108864
    float* h1c = (float*)(ws + 67108864);            // 512*64*128*4 = 16777216
    float* xz2 = (float*)(ws + 83886080);            // 16777216
    float* s1h = (float*)(ws + 100663296);           // 262144
    float* s1c = (float*)(ws + 100925440);           // 262144
    float* s2h = (float*)(ws + 101187584);           // 65536
    float* s2c = (float*)(ws + 101253120);           // 65536
    float* U1T = (float*)(ws + 101318656);           // 262144
    float* U2T = (float*)(ws + 101580800);           // 16384
    unsigned short* W1T = (unsigned short*)(ws + 101597184);  // 512*320*2*2 = 655360
    unsigned short* W2T = (unsigned short*)(ws + 102252544);  // 128*128*2*2 = 65536

    prep_weights<<<640, 256, 0, stream>>>(U1, U1T, U2, U2T, W1, W1T, W2, W2T);

    for (int c = 0; c < T_TOTAL / TC; c++) {
        const float* xchunk = x + (long)c * TC * D_IN;
        // xz1 = x_chunk @ W1 + b1   (M=32768, N=512, K=300)
        gemm_mfma_bias<<<dim3(G1 / 128, (BATCH * TC) / 128), 256, 0, stream>>>(
            xchunk, (long)D_IN, (long)T_TOTAL * D_IN, W1T, (long)512 * KP1,
            b1, xz1, G1, D_IN, KP1);
        // scan LSTM1 over this chunk
        lstm1_scan<<<BATCH / 2, 512, 0, stream>>>(xz1, U1T, h1c, s1h, s1c, c == 0);
        // xz2 = h1_chunk @ W2 + b2  (M=32768, N=128, K=128)
        gemm_mfma_bias<<<dim3(G2 / 128, (BATCH * TC) / 128), 256, 0, stream>>>(
            h1c, (long)H1, (long)TC * H1, W2T, (long)128 * 128,
            b2, xz2, G2, H1, H1);
        // scan LSTM2 over this chunk
        lstm2_scan<<<BATCH / 2, 128, 0, stream>>>(xz2, U2T, s2h, s2c, c == 0);
    }

    head_kernel<<<BATCH / 256, 256, 0, stream>>>(s2h, Wd, bd, out);
}